// Round 7
// baseline (285.477 us; speedup 1.0000x reference)
//
#include <hip/hip_runtime.h>
#include <math.h>

// Problem constants
#define B_   64
#define IC_  4096
#define NC_  16
#define D_   16
#define BSTR 136   // bf16 elements per LDS W row (128 + 8 pad); 68 u32, 16B-aligned rows
#define CH_  2     // i's per double-buffered W chunk

__device__ inline float dot8(const float4& a0, const float4& a1,
                             const float4& b0, const float4& b1) {
    float r = a0.x * b0.x;
    r = fmaf(a0.y, b0.y, r); r = fmaf(a0.z, b0.z, r); r = fmaf(a0.w, b0.w, r);
    r = fmaf(a1.x, b1.x, r); r = fmaf(a1.y, b1.y, r); r = fmaf(a1.z, b1.z, r);
    r = fmaf(a1.w, b1.w, r);
    return r;
}

// Pack two fp32 -> 2x bf16 in a u32 (round-to-nearest-even).
__device__ inline unsigned pack2_bf16(float a, float b) {
    unsigned ua = __float_as_uint(a), ub = __float_as_uint(b);
    ua += 0x7fffu + ((ua >> 16) & 1u);
    ub += 0x7fffu + ((ub >> 16) & 1u);
    return (ua >> 16) | (ub & 0xffff0000u);
}

__device__ inline float bf_lo(unsigned w) { return __uint_as_float(w << 16); }
__device__ inline float bf_hi(unsigned w) { return __uint_as_float(w & 0xffff0000u); }

// Sum-rotate within 16-lane DPP rows (the j dimension) on the VALU pipe.
// row_ror:N = 0x120|N. After rors 8,4,2,1 every lane holds the full 16-sum.
template <int CTRL>
__device__ inline float ror_add(float v) {
    int r = __builtin_amdgcn_update_dpp(0, __float_as_int(v), CTRL, 0xf, 0xf, false);
    return v + __int_as_float(r);
}

// Pass kernel. Block = 256 thr (4 waves): j = tid&15, c = (tid>>4)&3 (d-quad),
// wv = tid>>6. Wave wv owns 4 batches b0 = bg*16 + wv*4 (+bi serial). W staged
// into LDS as bf16 (RNE), double-buffered; x staged once in LDS fp32 (reads
// are wave-uniform broadcasts). Logits collapse to osum . u_hat; softmax over
// j: 2 shfl_xor (c-reduce) + 4 DPP ror-adds (j-sum, VALU pipe).
// Grid = 4*NI blocks: (bg 0..3) x (NI i-blocks).
__global__ __launch_bounds__(256, 4)
void caps_pass(const float* __restrict__ inp, const float* __restrict__ W,
               const float* __restrict__ osum, float* __restrict__ partials,
               int ipb, int use_osum)
{
    __shared__ unsigned wlds[2][CH_ * NC_ * (BSTR / 2)];  // 2 x 2176 u32 = 17408 B
    __shared__ float xlds[16 * 32 * 8];                   // 16 KB (ipb <= 32)

    const int tid = threadIdx.x;
    const int j   = tid & 15;
    const int c   = (tid >> 4) & 3;
    const int wv  = tid >> 6;

    // XCD-aware swizzle; the 4 bg's of an i-block stay adjacent (same XCD L2).
    const int n   = blockIdx.x;
    const int cpx = gridDim.x >> 3;
    const int wg  = (n & 7) * cpx + (n >> 3);
    const int ib  = wg >> 2;
    const int bg  = wg & 3;
    const int i0  = ib * ipb;
    const int b0  = bg * 16 + wv * 4;

    // ---- stage x slice [16 b][ipb i][8 e] fp32 into LDS (coalesced) ----
    {
        const int bl  = tid >> 4;      // 0..15
        const int ip2 = ipb * 2;       // float4 per batch row
        const float4* src =
            (const float4*)inp + (size_t)(bg * 16 + bl) * (IC_ * 2) + i0 * 2;
        float4* dst = (float4*)xlds + bl * ip2;
        for (int f = tid & 15; f < ip2; f += 16) dst[f] = src[f];
    }

    // ---- W staging: thread t covers row r = t>>4, 8-float group kp = t&15 ----
    const int r  = tid >> 4;   // 0..15
    const int kp = tid & 15;   // 0..15
    const float4* Wf4 = (const float4*)W;
    float4 pa0, pa1, pb0, pb1;

    // prologue: chunk 0 (i0, i0+1) -> buf 0
    pa0 = Wf4[((size_t)r * IC_ + i0) * 32 + kp * 2];
    pa1 = Wf4[((size_t)r * IC_ + i0) * 32 + kp * 2 + 1];
    pb0 = Wf4[((size_t)r * IC_ + i0 + 1) * 32 + kp * 2];
    pb1 = Wf4[((size_t)r * IC_ + i0 + 1) * 32 + kp * 2 + 1];
    {
        uint4 qa = make_uint4(pack2_bf16(pa0.x, pa0.y), pack2_bf16(pa0.z, pa0.w),
                              pack2_bf16(pa1.x, pa1.y), pack2_bf16(pa1.z, pa1.w));
        uint4 qb = make_uint4(pack2_bf16(pb0.x, pb0.y), pack2_bf16(pb0.z, pb0.w),
                              pack2_bf16(pb1.x, pb1.y), pack2_bf16(pb1.z, pb1.w));
        *(uint4*)&wlds[0][(r) * (BSTR / 2) + kp * 4]        = qa;
        *(uint4*)&wlds[0][(NC_ + r) * (BSTR / 2) + kp * 4]  = qb;
    }
    __syncthreads();

    // osum rows for my 4 batches (registers)
    float4 os[4];
    if (use_osum) {
#pragma unroll
        for (int bi = 0; bi < 4; ++bi)
            os[bi] = ((const float4*)osum)[((size_t)(b0 + bi) * 16 + j) * 4 + c];
    }

    float acc[4][4];
#pragma unroll
    for (int bi = 0; bi < 4; ++bi)
#pragma unroll
        for (int dl = 0; dl < 4; ++dl) acc[bi][dl] = 0.0f;

    const int nch = ipb >> 1;
    int cur = 0;
    for (int ch = 0; ch < nch; ++ch) {
        if (ch + 1 < nch) {  // prefetch next chunk (global -> regs, fp32)
            const int inx = i0 + (ch + 1) * 2;
            pa0 = Wf4[((size_t)r * IC_ + inx) * 32 + kp * 2];
            pa1 = Wf4[((size_t)r * IC_ + inx) * 32 + kp * 2 + 1];
            pb0 = Wf4[((size_t)r * IC_ + inx + 1) * 32 + kp * 2];
            pb1 = Wf4[((size_t)r * IC_ + inx + 1) * 32 + kp * 2 + 1];
        }
#pragma unroll
        for (int il = 0; il < CH_; ++il) {
            const int ilg = ch * 2 + il;
            // W row for (j, c-quad): 32 bf16 = 4 x ds_read_b128
            const unsigned* wrow = &wlds[cur][(il * NC_ + j) * (BSTR / 2) + c * 16];
            uint4 q0 = *(const uint4*)&wrow[0];
            uint4 q1 = *(const uint4*)&wrow[4];
            uint4 q2 = *(const uint4*)&wrow[8];
            uint4 q3 = *(const uint4*)&wrow[12];

            // x rows (wave-uniform broadcast reads)
            float4 xa[4], xb[4];
#pragma unroll
            for (int bi = 0; bi < 4; ++bi) {
                const float* xp = &xlds[((wv * 4 + bi) * ipb + ilg) * 8];
                xa[bi] = *(const float4*)&xp[0];
                xb[bi] = *(const float4*)&xp[4];
            }

            float uh[4][4];
#pragma unroll
            for (int dl = 0; dl < 4; ++dl) {
                uint4 qq = (dl == 0) ? q0 : (dl == 1) ? q1 : (dl == 2) ? q2 : q3;
                float4 wA = make_float4(bf_lo(qq.x), bf_hi(qq.x),
                                        bf_lo(qq.y), bf_hi(qq.y));
                float4 wB = make_float4(bf_lo(qq.z), bf_hi(qq.z),
                                        bf_lo(qq.w), bf_hi(qq.w));
#pragma unroll
                for (int bi = 0; bi < 4; ++bi)
                    uh[bi][dl] = dot8(wA, wB, xa[bi], xb[bi]);
            }

            float cc[4];
            if (use_osum) {
                float pb[4];
#pragma unroll
                for (int bi = 0; bi < 4; ++bi) {
                    float t = os[bi].x * uh[bi][0];
                    t = fmaf(os[bi].y, uh[bi][1], t);
                    t = fmaf(os[bi].z, uh[bi][2], t);
                    t = fmaf(os[bi].w, uh[bi][3], t);
                    pb[bi] = t;
                }
#pragma unroll
                for (int bi = 0; bi < 4; ++bi) {  // reduce over d-quads (c bits)
                    pb[bi] += __shfl_xor(pb[bi], 16);
                    pb[bi] += __shfl_xor(pb[bi], 32);
                }
#pragma unroll
                for (int bi = 0; bi < 4; ++bi) {
                    float e  = __expf(pb[bi]);      // no max-sub: |logit| small
                    float sm = ror_add<0x128>(e);   // sum over j via DPP rors
                    sm = ror_add<0x124>(sm);
                    sm = ror_add<0x122>(sm);
                    sm = ror_add<0x121>(sm);
                    cc[bi] = __fdividef(e, sm);
                }
            } else {
#pragma unroll
                for (int bi = 0; bi < 4; ++bi) cc[bi] = 0.0625f;
            }

#pragma unroll
            for (int bi = 0; bi < 4; ++bi)
#pragma unroll
                for (int dl = 0; dl < 4; ++dl)
                    acc[bi][dl] = fmaf(cc[bi], uh[bi][dl], acc[bi][dl]);
        }
        if (ch + 1 < nch) {  // convert + write prefetched chunk to other buffer
            const int nb = cur ^ 1;
            uint4 qa = make_uint4(pack2_bf16(pa0.x, pa0.y), pack2_bf16(pa0.z, pa0.w),
                                  pack2_bf16(pa1.x, pa1.y), pack2_bf16(pa1.z, pa1.w));
            uint4 qb = make_uint4(pack2_bf16(pb0.x, pb0.y), pack2_bf16(pb0.z, pb0.w),
                                  pack2_bf16(pb1.x, pb1.y), pack2_bf16(pb1.z, pb1.w));
            *(uint4*)&wlds[nb][(r) * (BSTR / 2) + kp * 4]       = qa;
            *(uint4*)&wlds[nb][(NC_ + r) * (BSTR / 2) + kp * 4] = qb;
        }
        __syncthreads();
        cur ^= 1;
    }

    // partials[ib][b][j][d], coalesced float4 stores
#pragma unroll
    for (int bi = 0; bi < 4; ++bi)
        ((float4*)partials)[(((size_t)ib * B_ + b0 + bi) * NC_ + j) * 4 + c] =
            make_float4(acc[bi][0], acc[bi][1], acc[bi][2], acc[bi][3]);
}

// Reduce over NI i-blocks + squash. Grid = 1024 blocks (one per (b,j) pair),
// 256 thr = 64 ksplit x 4 d-quads, float4 loads throughout.
// mode 0: osum = out ; mode 1: osum += out ; mode 2: d_out = out
__global__ __launch_bounds__(256)
void caps_reduce(const float* __restrict__ partials, float* __restrict__ osum,
                 float* __restrict__ outb, int NI, int mode)
{
    __shared__ float4 red[256];
    const int tid = threadIdx.x;
    const int o4  = tid & 3;
    const int ks  = tid >> 2;
    const int bj  = blockIdx.x;
    const float4* p4 = (const float4*)partials;

    float4 s = make_float4(0.f, 0.f, 0.f, 0.f);
    for (int ibk = ks; ibk < NI; ibk += 64) {
        float4 v = p4[(size_t)ibk * (B_ * NC_ * 4) + bj * 4 + o4];
        s.x += v.x; s.y += v.y; s.z += v.z; s.w += v.w;
    }
    red[tid] = s;
    __syncthreads();
    if (tid < 64) {
        float4 a = red[tid], b = red[tid + 64], c = red[tid + 128], d = red[tid + 192];
        s.x = a.x + b.x + c.x + d.x; s.y = a.y + b.y + c.y + d.y;
        s.z = a.z + b.z + c.z + d.z; s.w = a.w + b.w + c.w + d.w;
        red[tid] = s;
    }
    __syncthreads();
    if (tid < 4) {
        float4 t = red[tid];
#pragma unroll
        for (int kk = 1; kk < 16; ++kk) {
            float4 v = red[kk * 4 + tid];
            t.x += v.x; t.y += v.y; t.z += v.z; t.w += v.w;
        }
        float s2 = t.x * t.x + t.y * t.y + t.z * t.z + t.w * t.w;
        s2 += __shfl_xor(s2, 1);
        s2 += __shfl_xor(s2, 2);
        float scale = s2 / (1.0f + s2) * rsqrtf(s2 + 1e-7f);
        float4 o = make_float4(scale * t.x, scale * t.y, scale * t.z, scale * t.w);
        size_t fi = (size_t)bj * 4 + tid;
        if (mode == 0) ((float4*)osum)[fi] = o;
        else if (mode == 1) {
            float4 cu = ((float4*)osum)[fi];
            cu.x += o.x; cu.y += o.y; cu.z += o.z; cu.w += o.w;
            ((float4*)osum)[fi] = cu;
        } else ((float4*)outb)[fi] = o;
    }
}

extern "C" void kernel_launch(void* const* d_in, const int* in_sizes, int n_in,
                              void* d_out, int out_size, void* d_ws, size_t ws_size,
                              hipStream_t stream)
{
    const float* inp = (const float*)d_in[0];  // [64, 4096, 8]
    const float* W   = (const float*)d_in[1];  // [16, 4096, 16, 8]
    float* out  = (float*)d_out;               // [64, 16, 16]

    float* osum     = (float*)d_ws;                   // 16 KB used
    float* partials = (float*)((char*)d_ws + 65536);  // NI * 64 KB

    long cap = (long)(ws_size / 65536) - 1;  // NI units of 64 KB
    const int NI  = (cap >= 256) ? 256 : 128;
    const int ipb = IC_ / NI;                // 16 (or 32 fallback; xlds <= 32)
    dim3 grid(4 * NI);

    // iter 0: c uniform (softmax of zeros)
    caps_pass<<<grid, 256, 0, stream>>>(inp, W, osum, partials, ipb, 0);
    caps_reduce<<<1024, 256, 0, stream>>>(partials, osum, out, NI, 0);
    // iter 1: logits = out0 . u_hat
    caps_pass<<<grid, 256, 0, stream>>>(inp, W, osum, partials, ipb, 1);
    caps_reduce<<<1024, 256, 0, stream>>>(partials, osum, out, NI, 1);
    // iter 2: logits = (out0 + out1) . u_hat
    caps_pass<<<grid, 256, 0, stream>>>(inp, W, osum, partials, ipb, 1);
    caps_reduce<<<1024, 256, 0, stream>>>(partials, osum, out, NI, 2);
}

// Round 8
// 139.569 us; speedup vs baseline: 2.0454x; 2.0454x over previous
//
#include <hip/hip_runtime.h>
#include <math.h>

// Problem constants
#define B_   64
#define IC_  4096
#define NC_  16
#define D_   16
#define PADF 132   // 128 floats/row + 4 pad -> conflict-light W reads
#define CH_  2     // i's per double-buffered W chunk
#define IPB  16    // i's per block (NI = 256 i-blocks)

__device__ inline float dot8(const float4& a0, const float4& a1,
                             const float4& b0, const float4& b1) {
    float r = a0.x * b0.x;
    r = fmaf(a0.y, b0.y, r); r = fmaf(a0.z, b0.z, r); r = fmaf(a0.w, b0.w, r);
    r = fmaf(a1.x, b1.x, r); r = fmaf(a1.y, b1.y, r); r = fmaf(a1.z, b1.z, r);
    r = fmaf(a1.w, b1.w, r);
    return r;
}

// Sum-rotate within 16-lane DPP rows (the j dimension) on the VALU pipe.
// row_ror:N = 0x120|N. After rors 8,4,2,1 every lane holds the full 16-sum.
// Semantics HW-verified in rounds 5/6 (passed correctness).
template <int CTRL>
__device__ inline float ror_add(float v) {
    int r = __builtin_amdgcn_update_dpp(0, __float_as_int(v), CTRL, 0xf, 0xf, false);
    return v + __int_as_float(r);
}

// Pass kernel (R4 structure + DPP j-sum). Block = 512 thr (8 waves):
// j = tid&15, c = (tid>>4)&3 (d-quad), wv = tid>>6. Wave wv owns batches
// b0..b0+3 (b0 = bg*32 + wv*4). W fp32 double-buffered in LDS; x staged in
// LDS once per block (wave-uniform broadcast reads). Logits collapse to
// osum . u_hat; softmax over j: 2 shfl_xor (c-reduce) + 4 DPP ror-adds.
// Grid = 2*NI blocks -> (bg in 0..1) x (NI i-blocks).
__global__ __launch_bounds__(512, 4)
void caps_pass(const float* __restrict__ inp, const float* __restrict__ W,
               const float* __restrict__ osum, float* __restrict__ partials,
               int use_osum)
{
    __shared__ float wlds[2][CH_ * NC_ * PADF];  // 33792 B
    __shared__ float xlds[32 * IPB * 8];         // 16 KB

    const int tid = threadIdx.x;
    const int j   = tid & 15;
    const int c   = (tid >> 4) & 3;
    const int wv  = tid >> 6;

    // XCD-aware swizzle: contiguous work chunk per XCD; both bg of an i-block
    // land on the same XCD L2 (grid divisible by 8).
    const int n   = blockIdx.x;
    const int cpx = gridDim.x >> 3;
    const int wg  = (n & 7) * cpx + (n >> 3);
    const int ib  = wg >> 1;
    const int bg  = wg & 1;
    const int i0  = ib * IPB;
    const int b0  = bg * 32 + wv * 4;

    // ---- stage x slice [32 batches][IPB i][8 e] into LDS (coalesced) ----
    {
        const int b32 = tid >> 4;
        const int ip2 = IPB * 2;  // float4 per batch row
        const float4* src =
            (const float4*)inp + (size_t)(bg * 32 + b32) * (IC_ * 2) + i0 * 2;
        float4* dst = (float4*)xlds + b32 * ip2;
        for (int f = tid & 15; f < ip2; f += 16) dst[f] = src[f];
    }

    // ---- W staging: thread t stages float4 (jj = t>>5, kk = t&31)
    //      for il = 0 and il = 1 of each chunk ----
    const int jj = tid >> 5;   // 0..15
    const int kk = tid & 31;   // 0..31
    const float4* Wf4 = (const float4*)W;
    const size_t wbase = (size_t)jj * IC_ * 32 + kk;  // + i*32
    float4 s0, s1;

    // prologue: chunk 0
    s0 = Wf4[wbase + (size_t)(i0 + 0) * 32];
    s1 = Wf4[wbase + (size_t)(i0 + 1) * 32];
    *(float4*)&wlds[0][(jj) * PADF + kk * 4]       = s0;
    *(float4*)&wlds[0][(NC_ + jj) * PADF + kk * 4] = s1;
    __syncthreads();

    // osum rows for my 4 batches (registers)
    float4 os[4];
    if (use_osum) {
#pragma unroll
        for (int bi = 0; bi < 4; ++bi)
            os[bi] = ((const float4*)osum)[((size_t)(b0 + bi) * 16 + j) * 4 + c];
    }

    float acc[4][4];
#pragma unroll
    for (int bi = 0; bi < 4; ++bi)
#pragma unroll
        for (int dl = 0; dl < 4; ++dl) acc[bi][dl] = 0.0f;

    const int nch = IPB >> 1;
    int cur = 0;
    for (int ch = 0; ch < nch; ++ch) {
        if (ch + 1 < nch) {  // prefetch next chunk (global -> regs)
            const int inx = i0 + (ch + 1) * 2;
            s0 = Wf4[wbase + (size_t)(inx + 0) * 32];
            s1 = Wf4[wbase + (size_t)(inx + 1) * 32];
        }
#pragma unroll
        for (int il = 0; il < CH_; ++il) {
            const int ilg = ch * 2 + il;
            const float* row = &wlds[cur][(il * NC_ + j) * PADF + c * 32];
            float4 w0 = *(const float4*)&row[0],  w1 = *(const float4*)&row[4];
            float4 w2 = *(const float4*)&row[8],  w3 = *(const float4*)&row[12];
            float4 w4 = *(const float4*)&row[16], w5 = *(const float4*)&row[20];
            float4 w6 = *(const float4*)&row[24], w7 = *(const float4*)&row[28];

            float uh[4][4];
#pragma unroll
            for (int bi = 0; bi < 4; ++bi) {
                const float* xp = &xlds[(wv * 4 + bi) * (IPB * 8) + ilg * 8];
                float4 xa = *(const float4*)&xp[0];
                float4 xb = *(const float4*)&xp[4];
                uh[bi][0] = dot8(w0, w1, xa, xb);
                uh[bi][1] = dot8(w2, w3, xa, xb);
                uh[bi][2] = dot8(w4, w5, xa, xb);
                uh[bi][3] = dot8(w6, w7, xa, xb);
            }

            float cc[4];
            if (use_osum) {
                float pb[4];
#pragma unroll
                for (int bi = 0; bi < 4; ++bi) {
                    float r = os[bi].x * uh[bi][0];
                    r = fmaf(os[bi].y, uh[bi][1], r);
                    r = fmaf(os[bi].z, uh[bi][2], r);
                    r = fmaf(os[bi].w, uh[bi][3], r);
                    pb[bi] = r;
                }
#pragma unroll
                for (int bi = 0; bi < 4; ++bi) {  // reduce over d-quads (c bits)
                    pb[bi] += __shfl_xor(pb[bi], 16);
                    pb[bi] += __shfl_xor(pb[bi], 32);
                }
#pragma unroll
                for (int bi = 0; bi < 4; ++bi) {
                    float e  = __expf(pb[bi]);      // no max-sub: |logit| small
                    float sm = ror_add<0x128>(e);   // sum over j via DPP rors (VALU)
                    sm = ror_add<0x124>(sm);
                    sm = ror_add<0x122>(sm);
                    sm = ror_add<0x121>(sm);
                    cc[bi] = __fdividef(e, sm);
                }
            } else {
#pragma unroll
                for (int bi = 0; bi < 4; ++bi) cc[bi] = 0.0625f;
            }

#pragma unroll
            for (int bi = 0; bi < 4; ++bi)
#pragma unroll
                for (int dl = 0; dl < 4; ++dl)
                    acc[bi][dl] = fmaf(cc[bi], uh[bi][dl], acc[bi][dl]);
        }
        if (ch + 1 < nch) {  // write prefetched chunk to other buffer
            const int nb = cur ^ 1;
            *(float4*)&wlds[nb][(jj) * PADF + kk * 4]       = s0;
            *(float4*)&wlds[nb][(NC_ + jj) * PADF + kk * 4] = s1;
        }
        __syncthreads();
        cur ^= 1;
    }

    // partials[ib][b][j][d], coalesced float4 stores
#pragma unroll
    for (int bi = 0; bi < 4; ++bi)
        ((float4*)partials)[(((size_t)ib * B_ + b0 + bi) * NC_ + j) * 4 + c] =
            make_float4(acc[bi][0], acc[bi][1], acc[bi][2], acc[bi][3]);
}

// Reduce over NI i-blocks + squash. Grid = 1024 blocks (one per (b,j) pair),
// 256 thr = 64 ksplit x 4 d-quads, float4 loads throughout.
// mode 0: osum = out ; mode 1: osum += out ; mode 2: d_out = out
__global__ __launch_bounds__(256)
void caps_reduce(const float* __restrict__ partials, float* __restrict__ osum,
                 float* __restrict__ outb, int NI, int mode)
{
    __shared__ float4 red[256];
    const int tid = threadIdx.x;
    const int o4  = tid & 3;
    const int ks  = tid >> 2;
    const int bj  = blockIdx.x;
    const float4* p4 = (const float4*)partials;

    float4 s = make_float4(0.f, 0.f, 0.f, 0.f);
    for (int ibk = ks; ibk < NI; ibk += 64) {
        float4 v = p4[(size_t)ibk * (B_ * NC_ * 4) + bj * 4 + o4];
        s.x += v.x; s.y += v.y; s.z += v.z; s.w += v.w;
    }
    red[tid] = s;
    __syncthreads();
    if (tid < 64) {
        float4 a = red[tid], b = red[tid + 64], c = red[tid + 128], d = red[tid + 192];
        s.x = a.x + b.x + c.x + d.x; s.y = a.y + b.y + c.y + d.y;
        s.z = a.z + b.z + c.z + d.z; s.w = a.w + b.w + c.w + d.w;
        red[tid] = s;
    }
    __syncthreads();
    if (tid < 4) {
        float4 t = red[tid];
#pragma unroll
        for (int kk = 1; kk < 16; ++kk) {
            float4 v = red[kk * 4 + tid];
            t.x += v.x; t.y += v.y; t.z += v.z; t.w += v.w;
        }
        float s2 = t.x * t.x + t.y * t.y + t.z * t.z + t.w * t.w;
        s2 += __shfl_xor(s2, 1);
        s2 += __shfl_xor(s2, 2);
        float scale = s2 / (1.0f + s2) * rsqrtf(s2 + 1e-7f);
        float4 o = make_float4(scale * t.x, scale * t.y, scale * t.z, scale * t.w);
        size_t fi = (size_t)bj * 4 + tid;
        if (mode == 0) ((float4*)osum)[fi] = o;
        else if (mode == 1) {
            float4 cu = ((float4*)osum)[fi];
            cu.x += o.x; cu.y += o.y; cu.z += o.z; cu.w += o.w;
            ((float4*)osum)[fi] = cu;
        } else ((float4*)outb)[fi] = o;
    }
}

extern "C" void kernel_launch(void* const* d_in, const int* in_sizes, int n_in,
                              void* d_out, int out_size, void* d_ws, size_t ws_size,
                              hipStream_t stream)
{
    const float* inp = (const float*)d_in[0];  // [64, 4096, 8]
    const float* W   = (const float*)d_in[1];  // [16, 4096, 16, 8]
    float* out  = (float*)d_out;               // [64, 16, 16]

    float* osum     = (float*)d_ws;                   // 16 KB used
    float* partials = (float*)((char*)d_ws + 65536);  // NI * 64 KB

    const int NI = 256;            // ws_size >= 16.8 MB (verified by prior rounds)
    dim3 grid(2 * NI);

    // iter 0: c uniform (softmax of zeros)
    caps_pass<<<grid, 512, 0, stream>>>(inp, W, osum, partials, 0);
    caps_reduce<<<1024, 256, 0, stream>>>(partials, osum, out, NI, 0);
    // iter 1: logits = out0 . u_hat
    caps_pass<<<grid, 512, 0, stream>>>(inp, W, osum, partials, 1);
    caps_reduce<<<1024, 256, 0, stream>>>(partials, osum, out, NI, 1);
    // iter 2: logits = (out0 + out1) . u_hat
    caps_pass<<<grid, 512, 0, stream>>>(inp, W, osum, partials, 1);
    caps_reduce<<<1024, 256, 0, stream>>>(partials, osum, out, NI, 2);
}

// Round 10
// 113.621 us; speedup vs baseline: 2.5125x; 1.2284x over previous
//
#include <hip/hip_runtime.h>
#include <math.h>

// Problem constants
#define B_   64
#define IC_  4096
#define NC_  16
#define D_   16
#define IPB  16    // i's per block (NI = 256 i-blocks)
#define CH_  2     // i's per double-buffered W chunk
#define WROW 68    // u32 per W-LDS row: 64 data (128 f16) + 4 pad; 272B, 16B-aligned
#define XROW 68    // u32 per x-LDS batch row: 64 data + 4 pad

typedef __fp16 half2v __attribute__((ext_vector_type(2)));

#if __has_builtin(__builtin_amdgcn_fdot2)
#define HAVE_FDOT2 1
#else
#define HAVE_FDOT2 0
#endif

// pack 2 fp32 -> half2 in a u32 (v_cvt_pkrtz_f32_f16, single instr)
__device__ inline unsigned pk16(float a, float b) {
    half2v h = __builtin_amdgcn_cvt_pkrtz(a, b);
    return __builtin_bit_cast(unsigned, h);
}

// d = dot(w_half2, x_half2) + c with fp32 accumulate (v_dot2_f32_f16)
__device__ inline float hdot2(unsigned w, unsigned x, float cacc) {
#if HAVE_FDOT2
    return __builtin_amdgcn_fdot2(__builtin_bit_cast(half2v, w),
                                  __builtin_bit_cast(half2v, x), cacc, false);
#else
    half2v hw = __builtin_bit_cast(half2v, w);
    half2v hx = __builtin_bit_cast(half2v, x);
    return cacc + (float)hw.x * (float)hx.x + (float)hw.y * (float)hx.y;
#endif
}

// Sum-rotate within 16-lane DPP rows (the j dimension) on the VALU pipe.
// row_ror:N = 0x120|N. After rors 8,4,2,1 every lane holds the full 16-sum.
// HW-verified correct in rounds 5-7.
template <int CTRL>
__device__ inline float ror_add(float v) {
    int r = __builtin_amdgcn_update_dpp(0, __float_as_int(v), CTRL, 0xf, 0xf, false);
    return v + __int_as_float(r);
}

// Pass kernel (R7 structure, f16 W/x + v_dot2). Block = 512 thr (8 waves):
// j = tid&15, c = (tid>>4)&3 (d-quad), wv = tid>>6. Wave wv owns batches
// b0..b0+3 (b0 = bg*32 + wv*4). W staged to LDS as packed f16 (RTZ),
// double-buffered; x staged once as packed f16 (uniform broadcast reads).
// Logits collapse to osum . u_hat; softmax over j: 2 shfl_xor (c-reduce) +
// 4 DPP ror-adds. Grid = 2*NI blocks -> (bg in 0..1) x (NI i-blocks).
__global__ __launch_bounds__(512, 4)
void caps_pass(const float* __restrict__ inp, const float* __restrict__ W,
               const float* __restrict__ osum, float* __restrict__ partials,
               int use_osum)
{
    __shared__ unsigned wlds[2][CH_ * NC_ * WROW];  // 2 x 2176 u32 = 17408 B
    __shared__ unsigned xlds[32 * XROW];            // 2176 u32 = 8704 B

    const int tid = threadIdx.x;
    const int j   = tid & 15;
    const int c   = (tid >> 4) & 3;
    const int wv  = tid >> 6;

    // XCD-aware swizzle: both bg of an i-block land on the same XCD L2.
    const int n   = blockIdx.x;
    const int cpx = gridDim.x >> 3;
    const int wg  = (n & 7) * cpx + (n >> 3);
    const int ib  = wg >> 1;
    const int bg  = wg & 1;
    const int i0  = ib * IPB;
    const int b0  = bg * 32 + wv * 4;

    // ---- x stage: thread t handles (b = t>>4, il = t&15): 8 floats -> 4 u32 ----
    {
        const int xb = tid >> 4, xil = tid & 15;
        const float4* src =
            (const float4*)inp + ((size_t)(bg * 32 + xb) * IC_ + i0 + xil) * 2;
        float4 xa = src[0], xbv = src[1];
        *(uint4*)&xlds[xb * XROW + xil * 4] =
            make_uint4(pk16(xa.x, xa.y), pk16(xa.z, xa.w),
                       pk16(xbv.x, xbv.y), pk16(xbv.z, xbv.w));
    }

    // ---- W stage: thread t handles (row = t>>4 = il*16+j, col4 = t&15):
    //      one d-row (8 floats) of W[j, i0+il] -> uint4 ----
    const int srow = tid >> 4;   // il*16 + j
    const int scol = tid & 15;   // d index
    const int sil  = srow >> 4;
    const int sj   = srow & 15;
    const float4* Wf4 = (const float4*)W;
    const size_t wgbase = ((size_t)sj * IC_) * 32 + scol * 2;  // + i*32

    float4 g0, g1;
    g0 = Wf4[wgbase + (size_t)(i0 + sil) * 32];
    g1 = Wf4[wgbase + (size_t)(i0 + sil) * 32 + 1];
    *(uint4*)&wlds[0][srow * WROW + scol * 4] =
        make_uint4(pk16(g0.x, g0.y), pk16(g0.z, g0.w),
                   pk16(g1.x, g1.y), pk16(g1.z, g1.w));
    __syncthreads();

    // osum rows for my 4 batches (registers)
    float4 os[4];
    if (use_osum) {
#pragma unroll
        for (int bi = 0; bi < 4; ++bi)
            os[bi] = ((const float4*)osum)[((size_t)(b0 + bi) * 16 + j) * 4 + c];
    }

    float acc[4][4];
#pragma unroll
    for (int bi = 0; bi < 4; ++bi)
#pragma unroll
        for (int dl = 0; dl < 4; ++dl) acc[bi][dl] = 0.0f;

    const int nch = IPB / CH_;
    int cur = 0;
    for (int ch = 0; ch < nch; ++ch) {
        if (ch + 1 < nch) {  // prefetch next chunk's W (global -> regs)
            const int inx = i0 + (ch + 1) * CH_ + sil;
            g0 = Wf4[wgbase + (size_t)inx * 32];
            g1 = Wf4[wgbase + (size_t)inx * 32 + 1];
        }
#pragma unroll
        for (int il = 0; il < CH_; ++il) {
            const int ilg = ch * CH_ + il;
            // W c-chunk: 4 d-rows x 8 f16 = 16 u32 = 4 x ds_read_b128
            const unsigned* wr = &wlds[cur][(il * NC_ + j) * WROW + c * 16];
            uint4 q0 = *(const uint4*)&wr[0];
            uint4 q1 = *(const uint4*)&wr[4];
            uint4 q2 = *(const uint4*)&wr[8];
            uint4 q3 = *(const uint4*)&wr[12];

            // x for my 4 batches (uniform broadcast b128 reads)
            uint4 xh[4];
#pragma unroll
            for (int bi = 0; bi < 4; ++bi)
                xh[bi] = *(const uint4*)&xlds[(wv * 4 + bi) * XROW + ilg * 4];

            float uh[4][4];
#pragma unroll
            for (int dl = 0; dl < 4; ++dl) {
                uint4 qq = (dl == 0) ? q0 : (dl == 1) ? q1 : (dl == 2) ? q2 : q3;
#pragma unroll
                for (int bi = 0; bi < 4; ++bi) {
                    float r = hdot2(qq.x, xh[bi].x, 0.0f);
                    r = hdot2(qq.y, xh[bi].y, r);
                    r = hdot2(qq.z, xh[bi].z, r);
                    uh[bi][dl] = hdot2(qq.w, xh[bi].w, r);
                }
            }

            float cc[4];
            if (use_osum) {
                float pb[4];
#pragma unroll
                for (int bi = 0; bi < 4; ++bi) {
                    float t = os[bi].x * uh[bi][0];
                    t = fmaf(os[bi].y, uh[bi][1], t);
                    t = fmaf(os[bi].z, uh[bi][2], t);
                    t = fmaf(os[bi].w, uh[bi][3], t);
                    pb[bi] = t;
                }
#pragma unroll
                for (int bi = 0; bi < 4; ++bi) {  // reduce over d-quads (c bits)
                    pb[bi] += __shfl_xor(pb[bi], 16);
                    pb[bi] += __shfl_xor(pb[bi], 32);
                }
#pragma unroll
                for (int bi = 0; bi < 4; ++bi) {
                    float e  = __expf(pb[bi]);      // no max-sub: |logit| small
                    float sm = ror_add<0x128>(e);   // sum over j via DPP rors (VALU)
                    sm = ror_add<0x124>(sm);
                    sm = ror_add<0x122>(sm);
                    sm = ror_add<0x121>(sm);
                    cc[bi] = __fdividef(e, sm);
                }
            } else {
#pragma unroll
                for (int bi = 0; bi < 4; ++bi) cc[bi] = 0.0625f;
            }

#pragma unroll
            for (int bi = 0; bi < 4; ++bi)
#pragma unroll
                for (int dl = 0; dl < 4; ++dl)
                    acc[bi][dl] = fmaf(cc[bi], uh[bi][dl], acc[bi][dl]);
        }
        if (ch + 1 < nch) {  // convert + write prefetched W chunk to other buffer
            const int nb = cur ^ 1;
            *(uint4*)&wlds[nb][srow * WROW + scol * 4] =
                make_uint4(pk16(g0.x, g0.y), pk16(g0.z, g0.w),
                           pk16(g1.x, g1.y), pk16(g1.z, g1.w));
        }
        __syncthreads();
        cur ^= 1;
    }

    // partials[ib][b][j][d], float4 stores
#pragma unroll
    for (int bi = 0; bi < 4; ++bi)
        ((float4*)partials)[(((size_t)ib * B_ + b0 + bi) * NC_ + j) * 4 + c] =
            make_float4(acc[bi][0], acc[bi][1], acc[bi][2], acc[bi][3]);
}

// Reduce over NI i-blocks + squash. Grid = 1024 blocks (one per (b,j) pair),
// 256 thr = 64 ksplit x 4 d-quads, float4 loads throughout.
// mode 0: osum = out ; mode 1: osum += out ; mode 2: d_out = out
__global__ __launch_bounds__(256)
void caps_reduce(const float* __restrict__ partials, float* __restrict__ osum,
                 float* __restrict__ outb, int NI, int mode)
{
    __shared__ float4 red[256];
    const int tid = threadIdx.x;
    const int o4  = tid & 3;
    const int ks  = tid >> 2;
    const int bj  = blockIdx.x;
    const float4* p4 = (const float4*)partials;

    float4 s = make_float4(0.f, 0.f, 0.f, 0.f);
    for (int ibk = ks; ibk < NI; ibk += 64) {
        float4 v = p4[(size_t)ibk * (B_ * NC_ * 4) + bj * 4 + o4];
        s.x += v.x; s.y += v.y; s.z += v.z; s.w += v.w;
    }
    red[tid] = s;
    __syncthreads();
    if (tid < 64) {
        float4 a = red[tid], b = red[tid + 64], c = red[tid + 128], d = red[tid + 192];
        s.x = a.x + b.x + c.x + d.x; s.y = a.y + b.y + c.y + d.y;
        s.z = a.z + b.z + c.z + d.z; s.w = a.w + b.w + c.w + d.w;
        red[tid] = s;
    }
    __syncthreads();
    if (tid < 4) {
        float4 t = red[tid];
#pragma unroll
        for (int kk = 1; kk < 16; ++kk) {
            float4 v = red[kk * 4 + tid];
            t.x += v.x; t.y += v.y; t.z += v.z; t.w += v.w;
        }
        float s2 = t.x * t.x + t.y * t.y + t.z * t.z + t.w * t.w;
        s2 += __shfl_xor(s2, 1);
        s2 += __shfl_xor(s2, 2);
        float scale = s2 / (1.0f + s2) * rsqrtf(s2 + 1e-7f);
        float4 o = make_float4(scale * t.x, scale * t.y, scale * t.z, scale * t.w);
        size_t fi = (size_t)bj * 4 + tid;
        if (mode == 0) ((float4*)osum)[fi] = o;
        else if (mode == 1) {
            float4 cu = ((float4*)osum)[fi];
            cu.x += o.x; cu.y += o.y; cu.z += o.z; cu.w += o.w;
            ((float4*)osum)[fi] = cu;
        } else ((float4*)outb)[fi] = o;
    }
}

extern "C" void kernel_launch(void* const* d_in, const int* in_sizes, int n_in,
                              void* d_out, int out_size, void* d_ws, size_t ws_size,
                              hipStream_t stream)
{
    const float* inp = (const float*)d_in[0];  // [64, 4096, 8]
    const float* W   = (const float*)d_in[1];  // [16, 4096, 16, 8]
    float* out  = (float*)d_out;               // [64, 16, 16]

    float* osum     = (float*)d_ws;                   // 16 KB used
    float* partials = (float*)((char*)d_ws + 65536);  // NI * 64 KB

    const int NI = 256;            // ws verified >= 16.8 MB by prior rounds
    dim3 grid(2 * NI);

    // iter 0: c uniform (softmax of zeros)
    caps_pass<<<grid, 512, 0, stream>>>(inp, W, osum, partials, 0);
    caps_reduce<<<1024, 256, 0, stream>>>(partials, osum, out, NI, 0);
    // iter 1: logits = out0 . u_hat
    caps_pass<<<grid, 512, 0, stream>>>(inp, W, osum, partials, 1);
    caps_reduce<<<1024, 256, 0, stream>>>(partials, osum, out, NI, 1);
    // iter 2: logits = (out0 + out1) . u_hat
    caps_pass<<<grid, 512, 0, stream>>>(inp, W, osum, partials, 1);
    caps_reduce<<<1024, 256, 0, stream>>>(partials, osum, out, NI, 2);
}